// Round 2
// baseline (196.661 us; speedup 1.0000x reference)
//
#include <hip/hip_runtime.h>
#include <hip/hip_bf16.h>
#include <math.h>

// Problem constants (from reference setup_inputs)
#define B   16
#define NH  1024
#define NO  2048
#define DQ  24

#define ALPHA_FOCAL 0.25f
#define GAMMA_FOCAL 2.0f
#define MARGIN_PEN  0.005f
#define RADIUS_REP  0.015f

// ws float slots:
// 0: hand chamfer dir1 (sum over b,n of sqrt(min))        weight 1
// 1: hand chamfer dir2                                     weight 1
// 2: obj  chamfer dir1, weighted by has_contact[b]
// 3: obj  chamfer dir2, weighted
// 4: repulsion sum, weighted
// 5: penetration sum, weighted

__device__ inline float block_reduce_sum(float v, float* red) {
    // wave64 reduce
    #pragma unroll
    for (int off = 32; off > 0; off >>= 1) v += __shfl_down(v, off, 64);
    int lane = threadIdx.x & 63;
    int wid  = threadIdx.x >> 6;
    if (lane == 0) red[wid] = v;
    __syncthreads();
    float s = 0.f;
    if (threadIdx.x == 0) {
        s = red[0] + red[1] + red[2] + red[3];
    }
    __syncthreads();
    return s;   // valid in thread 0 only
}

// Segment layout (blocks of 256 threads):
//  S0 [  0, 64): hand chamfer dir1  P=pred_hand Q=gt_hand   (4 blocks/batch)
//  S1 [ 64,128): hand chamfer dir2  P=gt_hand   Q=pred_hand
//  S2 [128,256): obj  chamfer dir1  P=pred_obj  Q=gt_obj    (8 blocks/batch)
//  S3 [256,384): obj  chamfer dir2  P=gt_obj    Q=pred_obj
//  S4 [384,512): repulsion          P=pred_obj  Q=pred_obj
//  S5 [512,640): penetration        P=pred_obj  Q=pred_hand
__global__ __launch_bounds__(256) void pairwise_kernel(
    const float* __restrict__ pred_hand, const float* __restrict__ pred_obj,
    const float* __restrict__ gt_hand,   const float* __restrict__ gt_obj,
    const float* __restrict__ has_contact, float* __restrict__ ws)
{
    __shared__ float4 q[NO];        // 32 KiB max
    __shared__ float  red[4];

    int blk = blockIdx.x;
    int seg, local;
    if      (blk <  64) { seg = 0; local = blk;       }
    else if (blk < 128) { seg = 1; local = blk -  64; }
    else if (blk < 256) { seg = 2; local = blk - 128; }
    else if (blk < 384) { seg = 3; local = blk - 256; }
    else if (blk < 512) { seg = 4; local = blk - 384; }
    else                { seg = 5; local = blk - 512; }

    int bpb = (seg < 2) ? (NH / 256) : (NO / 256);
    int b     = local / bpb;
    int chunk = local % bpb;

    const float* Pbase; const float* Qbase; int NQl; int mode; int slot;
    switch (seg) {
        case 0:  Pbase = pred_hand + b*NH*3; Qbase = gt_hand   + b*NH*3; NQl = NH; mode = 0; slot = 0; break;
        case 1:  Pbase = gt_hand   + b*NH*3; Qbase = pred_hand + b*NH*3; NQl = NH; mode = 0; slot = 1; break;
        case 2:  Pbase = pred_obj  + b*NO*3; Qbase = gt_obj    + b*NO*3; NQl = NO; mode = 0; slot = 2; break;
        case 3:  Pbase = gt_obj    + b*NO*3; Qbase = pred_obj  + b*NO*3; NQl = NO; mode = 0; slot = 3; break;
        case 4:  Pbase = pred_obj  + b*NO*3; Qbase = pred_obj  + b*NO*3; NQl = NO; mode = 1; slot = 4; break;
        default: Pbase = pred_obj  + b*NO*3; Qbase = pred_hand + b*NH*3; NQl = NH; mode = 2; slot = 5; break;
    }

    // Stage Q into LDS as {x,y,z,|q|^2}
    for (int j = threadIdx.x; j < NQl; j += 256) {
        float x = Qbase[j*3+0];
        float y = Qbase[j*3+1];
        float z = Qbase[j*3+2];
        q[j] = make_float4(x, y, z, x*x + y*y + z*z);
    }
    __syncthreads();

    int n = chunk*256 + (int)threadIdx.x;
    float px = Pbase[n*3+0], py = Pbase[n*3+1], pz = Pbase[n*3+2];
    float pn = px*px + py*py + pz*pz;

    float val;
    if (mode == 1) {
        // repulsion: sum over j != n of relu(R - d)
        const float R2 = RADIUS_REP * RADIUS_REP;
        float s = 0.f;
        #pragma unroll 8
        for (int j = 0; j < NQl; ++j) {
            float4 Q4 = q[j];
            float t  = fmaf(px, Q4.x, fmaf(py, Q4.y, pz * Q4.z));
            float d2 = fmaf(-2.f, t, pn + Q4.w);
            if (d2 < R2 && j != n) {
                s += RADIUS_REP - sqrtf(fmaxf(d2, 1e-12f));
            }
        }
        val = s;
    } else {
        // chamfer / penetration: min over j of d^2
        float m = 1e30f;
        #pragma unroll 8
        for (int j = 0; j < NQl; ++j) {
            float4 Q4 = q[j];
            float t  = fmaf(px, Q4.x, fmaf(py, Q4.y, pz * Q4.z));
            float d2 = fmaf(-2.f, t, pn + Q4.w);
            m = fminf(m, d2);
        }
        float d = sqrtf(fmaxf(m, 1e-12f));
        val = (mode == 2) ? fmaxf(MARGIN_PEN - d, 0.f) : d;
    }

    float bs = block_reduce_sum(val, red);
    if (threadIdx.x == 0) {
        float w = (slot >= 2) ? has_contact[b] : 1.f;
        atomicAdd(&ws[slot], bs * w);
    }
}

__global__ __launch_bounds__(256) void finalize_kernel(
    const float* __restrict__ pred_pose, const float* __restrict__ pred_qpos,
    const float* __restrict__ logits,
    const float* __restrict__ gt_pose,   const float* __restrict__ gt_qpos,
    const float* __restrict__ gt_contact, const float* __restrict__ has_contact,
    const float* __restrict__ ws, float* __restrict__ out)
{
    __shared__ float red[4];
    int tid = threadIdx.x;

    // focal (contact) loss sum over B*NH
    float fsum = 0.f;
    for (int i = tid; i < B*NH; i += 256) {
        float l = logits[i];
        float y = gt_contact[i];
        float bce = fmaxf(l, 0.f) - l*y + log1pf(expf(-fabsf(l)));
        float pt  = expf(-bce);
        float om  = 1.f - pt;
        fsum += ALPHA_FOCAL * om * om * bce;
    }

    // qpos MSE sum over B*DQ
    float qsum = 0.f;
    for (int i = tid; i < B*DQ; i += 256) {
        float d = pred_qpos[i] - gt_qpos[i];
        qsum += d*d;
    }

    // pose loss (per batch, weighted) + valid sum
    float psum = 0.f, vsum = 0.f;
    if (tid < B) {
        const float* pp = pred_pose + tid*7;
        const float* gp = gt_pose   + tid*7;
        float lt = (fabsf(pp[0]-gp[0]) + fabsf(pp[1]-gp[1]) + fabsf(pp[2]-gp[2])) * (1.f/3.f);
        float npn = sqrtf(pp[3]*pp[3] + pp[4]*pp[4] + pp[5]*pp[5] + pp[6]*pp[6]);
        float ngn = sqrtf(gp[3]*gp[3] + gp[4]*gp[4] + gp[5]*gp[5] + gp[6]*gp[6]);
        float dot = (pp[3]*gp[3] + pp[4]*gp[4] + pp[5]*gp[5] + pp[6]*gp[6]) / (npn * ngn);
        float lr = 1.f - fabsf(dot);
        psum = (lt + 0.1f*lr) * has_contact[tid];
        vsum = has_contact[tid];
    }

    float fT = block_reduce_sum(fsum, red);
    float qT = block_reduce_sum(qsum, red);
    float pT = block_reduce_sum(psum, red);
    float vT = block_reduce_sum(vsum, red);

    if (tid == 0) {
        float valid = vT + 1e-6f;
        float loss_cd_hand = (ws[0] + ws[1]) * (1.f / (B * NH));
        float loss_cd_obj  = (ws[2] + ws[3]) / ((float)NO * valid);
        float loss_rep     =  ws[4] / ((float)NO * (float)NO * valid);
        float loss_pen     =  ws[5] / ((float)NO * valid);
        float loss_pose    =  pT / valid;
        float loss_qpos    =  qT * (1.f / (B * DQ));
        float loss_contact =  fT * (1.f / (B * NH));
        float total = 5.0f*loss_cd_hand + 5.0f*loss_cd_obj + 2.0f*loss_pose
                    + 1.0f*loss_qpos + 2.0f*loss_contact
                    + 0.5f*loss_rep + 0.5f*loss_pen;
        out[0] = total;
    }
}

extern "C" void kernel_launch(void* const* d_in, const int* in_sizes, int n_in,
                              void* d_out, int out_size, void* d_ws, size_t ws_size,
                              hipStream_t stream) {
    const float* pred_hand   = (const float*)d_in[0];
    const float* pred_obj    = (const float*)d_in[1];
    const float* pred_pose   = (const float*)d_in[2];
    const float* pred_qpos   = (const float*)d_in[3];
    const float* logits      = (const float*)d_in[4];
    const float* gt_hand     = (const float*)d_in[5];
    const float* gt_obj      = (const float*)d_in[6];
    const float* gt_pose     = (const float*)d_in[7];
    const float* gt_qpos     = (const float*)d_in[8];
    const float* gt_contact  = (const float*)d_in[9];
    const float* has_contact = (const float*)d_in[10];

    float* ws = (float*)d_ws;
    hipMemsetAsync(ws, 0, 6 * sizeof(float), stream);

    pairwise_kernel<<<640, 256, 0, stream>>>(pred_hand, pred_obj, gt_hand, gt_obj,
                                             has_contact, ws);
    finalize_kernel<<<1, 256, 0, stream>>>(pred_pose, pred_qpos, logits,
                                           gt_pose, gt_qpos, gt_contact, has_contact,
                                           ws, (float*)d_out);
}